// Round 1
// baseline (363.488 us; speedup 1.0000x reference)
//
#include <hip/hip_runtime.h>
#include <hip/hip_bf16.h>

// Problem constants (from reference): N=16, M=65536, FIN=32, FOUT=32, K=7
#define N_    16
#define M_    65536
#define FIN_  32
#define FOUT_ 32
#define K_    7

typedef __bf16 bf16x8 __attribute__((ext_vector_type(8)));
typedef float  f32x4  __attribute__((ext_vector_type(4)));

// out[n,m,o] = bias[o] + sum_k iv[m,k] * sum_f x[n, idx[m,k], f] * W[k,f,o]
// One wave handles one m at a time (grid-stride over m).
// Per (m,k): A = iv[m,k] * x[:, idx[m,k], :]  (16x32, bf16),
//            B = W[k]                          (32x32, bf16, two 16-col halves)
// mfma_f32_16x16x32_bf16 accumulates fp32 across k.
__global__ __launch_bounds__(256, 4)
void gfc_kernel(const float* __restrict__ x,
                const float* __restrict__ w,
                const float* __restrict__ bias,
                const int*   __restrict__ index_list,
                const float* __restrict__ index_value,
                float* __restrict__ out)
{
    const int lane  = threadIdx.x & 63;
    const int col   = lane & 15;   // A-row n / C-col o(within half) / B-col
    const int kgrp  = lane >> 4;   // 0..3 : which 8-wide f-chunk this lane holds

    const int waves_per_block = blockDim.x >> 6;
    const int wave_id     = blockIdx.x * waves_per_block + (threadIdx.x >> 6);
    const int total_waves = gridDim.x * waves_per_block;

    // ---- Preload B fragments for all k and both FOUT halves (56 VGPRs) ----
    // B layout for 16x16x32: lane L holds B[f=(L>>4)*8+j][o=h*16+(L&15)], j=0..7
    bf16x8 bfrag[K_][2];
    #pragma unroll
    for (int k = 0; k < K_; ++k) {
        #pragma unroll
        for (int h = 0; h < 2; ++h) {
            const float* wp = w + (size_t)k * (FIN_ * FOUT_)
                                + (size_t)(kgrp * 8) * FOUT_ + h * 16 + col;
            bf16x8 b;
            #pragma unroll
            for (int j = 0; j < 8; ++j)
                b[j] = (__bf16)wp[j * FOUT_];
            bfrag[k][h] = b;
        }
    }
    const float b_lo = bias[col];
    const float b_hi = bias[16 + col];

    for (int m = wave_id; m < M_; m += total_waves) {
        f32x4 acc0 = {0.f, 0.f, 0.f, 0.f};
        f32x4 acc1 = {0.f, 0.f, 0.f, 0.f};

        #pragma unroll
        for (int k = 0; k < K_; ++k) {
            const int   m2  = index_list[m * K_ + k];
            const float ivk = index_value[m * K_ + k];

            // A layout for 16x16x32: lane L holds A[n=L&15][f=(L>>4)*8+j], j=0..7
            // x row (n, m2) is 128 B aligned-contiguous: two float4 loads.
            const float* ap = x + ((size_t)col * M_ + (size_t)m2) * FIN_ + kgrp * 8;
            const float4 v0 = *(const float4*)(ap);
            const float4 v1 = *(const float4*)(ap + 4);

            const float av[8] = {v0.x, v0.y, v0.z, v0.w, v1.x, v1.y, v1.z, v1.w};
            bf16x8 a;
            #pragma unroll
            for (int j = 0; j < 8; ++j)
                a[j] = (__bf16)(av[j] * ivk);   // fold iv scale into bf16 convert

            acc0 = __builtin_amdgcn_mfma_f32_16x16x32_bf16(a, bfrag[k][0], acc0, 0, 0, 0);
            acc1 = __builtin_amdgcn_mfma_f32_16x16x32_bf16(a, bfrag[k][1], acc1, 0, 0, 0);
        }

        // C/D layout: col = lane&15 (=o within half), row = (lane>>4)*4 + r (=n)
        #pragma unroll
        for (int r = 0; r < 4; ++r) {
            const int n = kgrp * 4 + r;
            const size_t base = ((size_t)n * M_ + (size_t)m) * FOUT_;
            out[base + col]      = acc0[r] + b_lo;
            out[base + 16 + col] = acc1[r] + b_hi;
        }
    }
}

extern "C" void kernel_launch(void* const* d_in, const int* in_sizes, int n_in,
                              void* d_out, int out_size, void* d_ws, size_t ws_size,
                              hipStream_t stream) {
    const float* x    = (const float*)d_in[0];  // (N, M, FIN) fp32
    const float* w    = (const float*)d_in[1];  // (K, FIN, FOUT) fp32
    const float* bias = (const float*)d_in[2];  // (FOUT,) fp32
    const int*   il   = (const int*)  d_in[3];  // (M*K,) int32
    const float* iv   = (const float*)d_in[4];  // (M, K) fp32
    float* out = (float*)d_out;                 // (N, M, FOUT) fp32

    // 2048 blocks x 4 waves = 8192 waves; 8 m per wave.
    dim3 grid(2048), block(256);
    hipLaunchKernelGGL(gfc_kernel, grid, block, 0, stream, x, w, bias, il, iv, out);
}

// Round 2
// 314.466 us; speedup vs baseline: 1.1559x; 1.1559x over previous
//
#include <hip/hip_runtime.h>
#include <hip/hip_bf16.h>

// Problem constants: N=16, M=65536, FIN=32, FOUT=32, K=7
#define N_    16
#define M_    65536
#define FIN_  32
#define FOUT_ 32
#define K_    7

typedef __bf16 bf16x8 __attribute__((ext_vector_type(8)));
typedef float  f32x4  __attribute__((ext_vector_type(4)));

// ---------------------------------------------------------------------------
// Pass 1: x (N,M,FIN) fp32  ->  xT (M,N,FIN) bf16 in workspace.
// tid -> (m, n, f8): lane L of a wave covers all (n, f8) for one m, so the
// 1 KB destination block xT[m] is written fully-coalesced (lane L writes 16 B
// at m*1024 + L*16). Reads: 16 distinct 128 B lines per wave, each fully used.
// ---------------------------------------------------------------------------
__global__ __launch_bounds__(256)
void transpose_kernel(const float* __restrict__ x, __bf16* __restrict__ xT)
{
    const int tid = blockIdx.x * blockDim.x + threadIdx.x;  // N_*M_*FIN_/8 total
    const int f8 = tid & 3;          // which 8-float chunk of the 32-f row
    const int n  = (tid >> 2) & 15;
    const int m  = tid >> 6;

    const float4* src = (const float4*)(x + ((size_t)n * M_ + m) * FIN_ + f8 * 8);
    const float4 v0 = src[0];
    const float4 v1 = src[1];
    const float av[8] = {v0.x, v0.y, v0.z, v0.w, v1.x, v1.y, v1.z, v1.w};

    bf16x8 b;
    #pragma unroll
    for (int j = 0; j < 8; ++j) b[j] = (__bf16)av[j];

    *(bf16x8*)(xT + ((size_t)m * N_ + n) * FIN_ + f8 * 8) = b;
}

// ---------------------------------------------------------------------------
// Pass 2: per (m,k) gather one contiguous 1 KB bf16 block xT[idx[m,k]],
// scale by iv[m,k] during repack, mfma_f32_16x16x32_bf16 accumulate over k.
// ---------------------------------------------------------------------------
__global__ __launch_bounds__(256, 4)
void gfc_bf16_kernel(const __bf16* __restrict__ xT,
                     const float* __restrict__ w,
                     const float* __restrict__ bias,
                     const int*   __restrict__ index_list,
                     const float* __restrict__ index_value,
                     float* __restrict__ out)
{
    const int lane  = threadIdx.x & 63;
    const int col   = lane & 15;   // A-row n / C-col o(within half) / B-col
    const int kgrp  = lane >> 4;   // which 8-wide f-chunk this lane holds

    const int waves_per_block = blockDim.x >> 6;
    const int wave_id     = blockIdx.x * waves_per_block + (threadIdx.x >> 6);
    const int total_waves = gridDim.x * waves_per_block;

    // B fragments for all k, both FOUT halves (56 VGPRs), from 28 KB weight.
    bf16x8 bfrag[K_][2];
    #pragma unroll
    for (int k = 0; k < K_; ++k) {
        #pragma unroll
        for (int h = 0; h < 2; ++h) {
            const float* wp = w + (size_t)k * (FIN_ * FOUT_)
                                + (size_t)(kgrp * 8) * FOUT_ + h * 16 + col;
            bf16x8 b;
            #pragma unroll
            for (int j = 0; j < 8; ++j)
                b[j] = (__bf16)wp[j * FOUT_];
            bfrag[k][h] = b;
        }
    }
    const float b_lo = bias[col];
    const float b_hi = bias[16 + col];

    // Byte offset of this lane's A-fragment inside a 1 KB xT[m2] block:
    // A[n=col][f=kgrp*8 + j]  ->  element (col*32 + kgrp*8)
    const size_t lane_elt = (size_t)col * FIN_ + kgrp * 8;

    for (int m0 = wave_id; m0 < M_; m0 += total_waves) {
        // m is wave-uniform: force scalar loads for idx/iv.
        const int m = __builtin_amdgcn_readfirstlane(m0);

        f32x4 acc0 = {0.f, 0.f, 0.f, 0.f};
        f32x4 acc1 = {0.f, 0.f, 0.f, 0.f};

        int   idxs[K_];
        float ivs[K_];
        #pragma unroll
        for (int k = 0; k < K_; ++k) {
            idxs[k] = index_list[m * K_ + k];
            ivs[k]  = index_value[m * K_ + k];
        }

        // Issue all 7 gathers (one 16 B load each) before consuming.
        bf16x8 raw[K_];
        #pragma unroll
        for (int k = 0; k < K_; ++k)
            raw[k] = *(const bf16x8*)(xT + (size_t)idxs[k] * (N_ * FIN_) + lane_elt);

        #pragma unroll
        for (int k = 0; k < K_; ++k) {
            const float ivk = ivs[k];
            bf16x8 a;
            #pragma unroll
            for (int j = 0; j < 8; ++j)
                a[j] = (__bf16)((float)raw[k][j] * ivk);
            acc0 = __builtin_amdgcn_mfma_f32_16x16x32_bf16(a, bfrag[k][0], acc0, 0, 0, 0);
            acc1 = __builtin_amdgcn_mfma_f32_16x16x32_bf16(a, bfrag[k][1], acc1, 0, 0, 0);
        }

        // C/D layout: col = lane&15 (=o within half), row = kgrp*4 + r (=n)
        #pragma unroll
        for (int r = 0; r < 4; ++r) {
            const int n = kgrp * 4 + r;
            const size_t base = ((size_t)n * M_ + (size_t)m0) * FOUT_;
            out[base + col]      = acc0[r] + b_lo;
            out[base + 16 + col] = acc1[r] + b_hi;
        }
    }
}

// ---------------------------------------------------------------------------
// Fallback (round-1 kernel) if ws_size is too small for the bf16 staging.
// ---------------------------------------------------------------------------
__global__ __launch_bounds__(256, 4)
void gfc_fallback_kernel(const float* __restrict__ x,
                         const float* __restrict__ w,
                         const float* __restrict__ bias,
                         const int*   __restrict__ index_list,
                         const float* __restrict__ index_value,
                         float* __restrict__ out)
{
    const int lane  = threadIdx.x & 63;
    const int col   = lane & 15;
    const int kgrp  = lane >> 4;

    const int waves_per_block = blockDim.x >> 6;
    const int wave_id     = blockIdx.x * waves_per_block + (threadIdx.x >> 6);
    const int total_waves = gridDim.x * waves_per_block;

    bf16x8 bfrag[K_][2];
    #pragma unroll
    for (int k = 0; k < K_; ++k) {
        #pragma unroll
        for (int h = 0; h < 2; ++h) {
            const float* wp = w + (size_t)k * (FIN_ * FOUT_)
                                + (size_t)(kgrp * 8) * FOUT_ + h * 16 + col;
            bf16x8 b;
            #pragma unroll
            for (int j = 0; j < 8; ++j)
                b[j] = (__bf16)wp[j * FOUT_];
            bfrag[k][h] = b;
        }
    }
    const float b_lo = bias[col];
    const float b_hi = bias[16 + col];

    for (int m = wave_id; m < M_; m += total_waves) {
        f32x4 acc0 = {0.f, 0.f, 0.f, 0.f};
        f32x4 acc1 = {0.f, 0.f, 0.f, 0.f};

        #pragma unroll
        for (int k = 0; k < K_; ++k) {
            const int   m2  = index_list[m * K_ + k];
            const float ivk = index_value[m * K_ + k];
            const float* ap = x + ((size_t)col * M_ + (size_t)m2) * FIN_ + kgrp * 8;
            const float4 v0 = *(const float4*)(ap);
            const float4 v1 = *(const float4*)(ap + 4);
            const float av[8] = {v0.x, v0.y, v0.z, v0.w, v1.x, v1.y, v1.z, v1.w};
            bf16x8 a;
            #pragma unroll
            for (int j = 0; j < 8; ++j)
                a[j] = (__bf16)(av[j] * ivk);
            acc0 = __builtin_amdgcn_mfma_f32_16x16x32_bf16(a, bfrag[k][0], acc0, 0, 0, 0);
            acc1 = __builtin_amdgcn_mfma_f32_16x16x32_bf16(a, bfrag[k][1], acc1, 0, 0, 0);
        }

        #pragma unroll
        for (int r = 0; r < 4; ++r) {
            const int n = kgrp * 4 + r;
            const size_t base = ((size_t)n * M_ + (size_t)m) * FOUT_;
            out[base + col]      = acc0[r] + b_lo;
            out[base + 16 + col] = acc1[r] + b_hi;
        }
    }
}

extern "C" void kernel_launch(void* const* d_in, const int* in_sizes, int n_in,
                              void* d_out, int out_size, void* d_ws, size_t ws_size,
                              hipStream_t stream) {
    const float* x    = (const float*)d_in[0];  // (N, M, FIN) fp32
    const float* w    = (const float*)d_in[1];  // (K, FIN, FOUT) fp32
    const float* bias = (const float*)d_in[2];  // (FOUT,) fp32
    const int*   il   = (const int*)  d_in[3];  // (M*K,) int32
    const float* iv   = (const float*)d_in[4];  // (M, K) fp32
    float* out = (float*)d_out;                 // (N, M, FOUT) fp32

    const size_t ws_needed = (size_t)M_ * N_ * FIN_ * sizeof(__bf16);  // 64 MB
    if (ws_size >= ws_needed) {
        __bf16* xT = (__bf16*)d_ws;
        // Pass 1: N*M*FIN/8 threads, 8 elements each.
        const int t_total  = N_ * M_ * FIN_ / 8;
        hipLaunchKernelGGL(transpose_kernel, dim3(t_total / 256), dim3(256), 0, stream,
                           x, xT);
        // Pass 2: 2048 blocks x 4 waves, 8 m per wave.
        hipLaunchKernelGGL(gfc_bf16_kernel, dim3(2048), dim3(256), 0, stream,
                           xT, w, bias, il, iv, out);
    } else {
        hipLaunchKernelGGL(gfc_fallback_kernel, dim3(2048), dim3(256), 0, stream,
                           x, w, bias, il, iv, out);
    }
}

// Round 3
// 310.051 us; speedup vs baseline: 1.1723x; 1.0142x over previous
//
#include <hip/hip_runtime.h>
#include <hip/hip_bf16.h>

// Problem constants: N=16, M=65536, FIN=32, FOUT=32, K=7
#define N_    16
#define M_    65536
#define FIN_  32
#define FOUT_ 32
#define K_    7

#define TOTAL_WAVES_ 8192           // 2048 blocks x 4 waves
#define ITERS_       (M_ / TOTAL_WAVES_)   // 8 m per wave

typedef __bf16 bf16x8 __attribute__((ext_vector_type(8)));
typedef float  f32x4  __attribute__((ext_vector_type(4)));

// ---------------------------------------------------------------------------
// Pass 1: x (N,M,FIN) fp32  ->  xT (M,N,FIN) bf16 in workspace.
// ---------------------------------------------------------------------------
__global__ __launch_bounds__(256)
void transpose_kernel(const float* __restrict__ x, __bf16* __restrict__ xT)
{
    const int tid = blockIdx.x * blockDim.x + threadIdx.x;  // N*M*FIN/8 threads
    const int f8 = tid & 3;
    const int n  = (tid >> 2) & 15;
    const int m  = tid >> 6;

    const float4* src = (const float4*)(x + ((size_t)n * M_ + m) * FIN_ + f8 * 8);
    const float4 v0 = src[0];
    const float4 v1 = src[1];
    const float av[8] = {v0.x, v0.y, v0.z, v0.w, v1.x, v1.y, v1.z, v1.w};

    bf16x8 b;
    #pragma unroll
    for (int j = 0; j < 8; ++j) b[j] = (__bf16)av[j];

    *(bf16x8*)(xT + ((size_t)m * N_ + n) * FIN_ + f8 * 8) = b;
}

// ---------------------------------------------------------------------------
// Pass 2, software-pipelined: while computing m_i, the idx/iv scalar loads
// for m_{i+1} and the 7 gathers for m_{i+1} are in flight (one full
// iteration of latency budget each). Stores are nontemporal so the 131 MB
// write-once stream doesn't evict gathered xT lines from L2.
// ---------------------------------------------------------------------------
__global__ __launch_bounds__(256, 4)
void gfc_bf16_kernel(const __bf16* __restrict__ xT,
                     const float* __restrict__ w,
                     const float* __restrict__ bias,
                     const int*   __restrict__ index_list,
                     const float* __restrict__ index_value,
                     float* __restrict__ out)
{
    const int lane  = threadIdx.x & 63;
    const int col   = lane & 15;   // A-row n / C-col o(within half) / B-col
    const int kgrp  = lane >> 4;   // which 8-wide f-chunk this lane holds

    const int waves_per_block = blockDim.x >> 6;
    const int wave_id = blockIdx.x * waves_per_block + (threadIdx.x >> 6);

    // B fragments for all k, both FOUT halves, from the 28 KB weight (L1-hot).
    bf16x8 bfrag[K_][2];
    #pragma unroll
    for (int k = 0; k < K_; ++k) {
        #pragma unroll
        for (int h = 0; h < 2; ++h) {
            const float* wp = w + (size_t)k * (FIN_ * FOUT_)
                                + (size_t)(kgrp * 8) * FOUT_ + h * 16 + col;
            bf16x8 b;
            #pragma unroll
            for (int j = 0; j < 8; ++j)
                b[j] = (__bf16)wp[j * FOUT_];
            bfrag[k][h] = b;
        }
    }
    const float b_lo = bias[col];
    const float b_hi = bias[16 + col];

    // Lane's element offset inside a 1 KB xT block: A[n=col][f=kgrp*8+j]
    const size_t lane_elt = (size_t)col * FIN_ + kgrp * 8;

    // ---- Pipeline prologue: idx/iv + gathers for the first m ----
    int m = __builtin_amdgcn_readfirstlane(wave_id);

    int   idxs[K_];
    float ivs[K_];
    #pragma unroll
    for (int k = 0; k < K_; ++k) {
        idxs[k] = index_list[m * K_ + k];
        ivs[k]  = index_value[m * K_ + k];
    }
    bf16x8 raw[K_];
    #pragma unroll
    for (int k = 0; k < K_; ++k)
        raw[k] = *(const bf16x8*)(xT + (size_t)idxs[k] * (N_ * FIN_) + lane_elt);

    for (int i = 0; i < ITERS_; ++i) {
        const bool has_next = (i + 1) < ITERS_;
        const int  m_next   = __builtin_amdgcn_readfirstlane(m + TOTAL_WAVES_);

        // 1) Kick off next iteration's scalar idx/iv loads immediately.
        int   idxn[K_];
        float ivn[K_];
        if (has_next) {
            #pragma unroll
            for (int k = 0; k < K_; ++k) {
                idxn[k] = index_list[m_next * K_ + k];
                ivn[k]  = index_value[m_next * K_ + k];
            }
        }

        // 2) Compute with the gathers issued one iteration ago.
        f32x4 acc0 = {0.f, 0.f, 0.f, 0.f};
        f32x4 acc1 = {0.f, 0.f, 0.f, 0.f};
        #pragma unroll
        for (int k = 0; k < K_; ++k) {
            const float ivk = ivs[k];
            bf16x8 a;
            #pragma unroll
            for (int j = 0; j < 8; ++j)
                a[j] = (__bf16)((float)raw[k][j] * ivk);
            acc0 = __builtin_amdgcn_mfma_f32_16x16x32_bf16(a, bfrag[k][0], acc0, 0, 0, 0);
            acc1 = __builtin_amdgcn_mfma_f32_16x16x32_bf16(a, bfrag[k][1], acc1, 0, 0, 0);
        }

        // 3) raw[] is consumed — issue next iteration's gathers now so they
        //    overlap the epilogue stores and next iteration's VALU.
        if (has_next) {
            #pragma unroll
            for (int k = 0; k < K_; ++k)
                raw[k] = *(const bf16x8*)(xT + (size_t)idxn[k] * (N_ * FIN_) + lane_elt);
            #pragma unroll
            for (int k = 0; k < K_; ++k) {
                idxs[k] = idxn[k];
                ivs[k]  = ivn[k];
            }
        }

        // 4) Epilogue: C/D layout col=lane&15 (=o half), row=kgrp*4+r (=n).
        //    Nontemporal: out is write-once, keep it out of L2.
        #pragma unroll
        for (int r = 0; r < 4; ++r) {
            const int n = kgrp * 4 + r;
            float* op = out + ((size_t)n * M_ + (size_t)m) * FOUT_;
            __builtin_nontemporal_store(acc0[r] + b_lo, op + col);
            __builtin_nontemporal_store(acc1[r] + b_hi, op + 16 + col);
        }

        m = m_next;
    }
}

// ---------------------------------------------------------------------------
// Fallback (round-1 kernel) if ws_size is too small for the bf16 staging.
// ---------------------------------------------------------------------------
__global__ __launch_bounds__(256, 4)
void gfc_fallback_kernel(const float* __restrict__ x,
                         const float* __restrict__ w,
                         const float* __restrict__ bias,
                         const int*   __restrict__ index_list,
                         const float* __restrict__ index_value,
                         float* __restrict__ out)
{
    const int lane  = threadIdx.x & 63;
    const int col   = lane & 15;
    const int kgrp  = lane >> 4;

    const int waves_per_block = blockDim.x >> 6;
    const int wave_id     = blockIdx.x * waves_per_block + (threadIdx.x >> 6);
    const int total_waves = gridDim.x * waves_per_block;

    bf16x8 bfrag[K_][2];
    #pragma unroll
    for (int k = 0; k < K_; ++k) {
        #pragma unroll
        for (int h = 0; h < 2; ++h) {
            const float* wp = w + (size_t)k * (FIN_ * FOUT_)
                                + (size_t)(kgrp * 8) * FOUT_ + h * 16 + col;
            bf16x8 b;
            #pragma unroll
            for (int j = 0; j < 8; ++j)
                b[j] = (__bf16)wp[j * FOUT_];
            bfrag[k][h] = b;
        }
    }
    const float b_lo = bias[col];
    const float b_hi = bias[16 + col];

    for (int m = wave_id; m < M_; m += total_waves) {
        f32x4 acc0 = {0.f, 0.f, 0.f, 0.f};
        f32x4 acc1 = {0.f, 0.f, 0.f, 0.f};

        #pragma unroll
        for (int k = 0; k < K_; ++k) {
            const int   m2  = index_list[m * K_ + k];
            const float ivk = index_value[m * K_ + k];
            const float* ap = x + ((size_t)col * M_ + (size_t)m2) * FIN_ + kgrp * 8;
            const float4 v0 = *(const float4*)(ap);
            const float4 v1 = *(const float4*)(ap + 4);
            const float av[8] = {v0.x, v0.y, v0.z, v0.w, v1.x, v1.y, v1.z, v1.w};
            bf16x8 a;
            #pragma unroll
            for (int j = 0; j < 8; ++j)
                a[j] = (__bf16)(av[j] * ivk);
            acc0 = __builtin_amdgcn_mfma_f32_16x16x32_bf16(a, bfrag[k][0], acc0, 0, 0, 0);
            acc1 = __builtin_amdgcn_mfma_f32_16x16x32_bf16(a, bfrag[k][1], acc1, 0, 0, 0);
        }

        #pragma unroll
        for (int r = 0; r < 4; ++r) {
            const int n = kgrp * 4 + r;
            const size_t base = ((size_t)n * M_ + (size_t)m) * FOUT_;
            out[base + col]      = acc0[r] + b_lo;
            out[base + 16 + col] = acc1[r] + b_hi;
        }
    }
}

extern "C" void kernel_launch(void* const* d_in, const int* in_sizes, int n_in,
                              void* d_out, int out_size, void* d_ws, size_t ws_size,
                              hipStream_t stream) {
    const float* x    = (const float*)d_in[0];  // (N, M, FIN) fp32
    const float* w    = (const float*)d_in[1];  // (K, FIN, FOUT) fp32
    const float* bias = (const float*)d_in[2];  // (FOUT,) fp32
    const int*   il   = (const int*)  d_in[3];  // (M*K,) int32
    const float* iv   = (const float*)d_in[4];  // (M, K) fp32
    float* out = (float*)d_out;                 // (N, M, FOUT) fp32

    const size_t ws_needed = (size_t)M_ * N_ * FIN_ * sizeof(__bf16);  // 64 MB
    if (ws_size >= ws_needed) {
        __bf16* xT = (__bf16*)d_ws;
        const int t_total = N_ * M_ * FIN_ / 8;
        hipLaunchKernelGGL(transpose_kernel, dim3(t_total / 256), dim3(256), 0, stream,
                           x, xT);
        // 2048 blocks x 4 waves = TOTAL_WAVES_; ITERS_ m per wave.
        hipLaunchKernelGGL(gfc_bf16_kernel, dim3(2048), dim3(256), 0, stream,
                           xT, w, bias, il, iv, out);
    } else {
        hipLaunchKernelGGL(gfc_fallback_kernel, dim3(2048), dim3(256), 0, stream,
                           x, w, bias, il, iv, out);
    }
}